// Round 2
// baseline (4235.618 us; speedup 1.0000x reference)
//
#include <hip/hip_runtime.h>
#include <hip/hip_bf16.h>

// MemoryRotaryAttend: rope(q), rope(k), concat k/v after mem_kv prefix, full softmax attention.
// Shapes fixed by setup_inputs(): q/k/v fp32 (4,32,512,128), mem_kv fp32 (2,4,4096,32,128),
// start_pos int scalar (=2048). Output fp32 (4,32,512,128).
#define BB   4
#define NN   32
#define SS   512
#define DD   128
#define NMEM 4096
#define MAXB 4
#define MQ   16            // query rows per block
#define NK   32            // key cols per tile
#define KSTR (DD + 4)      // LDS row stride in floats (pad: 2-way max bank aliasing on QK reads, free)
#define PSTR (NK + 4)

__global__ __launch_bounds__(256)
void mra_attn(const float* __restrict__ qg,
              const float* __restrict__ kg,
              const float* __restrict__ vg,
              const float* __restrict__ mg,
              const int*  __restrict__ spp,
              float* __restrict__ outg)
{
    const int start_pos = spp[0];
    const int T = start_pos + SS;
    const int ntiles = (T + NK - 1) / NK;

    const int qt    = blockIdx.x;   // query tile within S
    const int head  = blockIdx.y;
    const int batch = blockIdx.z;
    const int tid   = threadIdx.x;
    const int qrow  = tid >> 4;     // 0..15
    const int l16   = tid & 15;     // 0..15

    __shared__ float q_s[MQ * KSTR];
    __shared__ float k_s[NK * KSTR];
    __shared__ float v_s[NK * KSTR];
    __shared__ float p_s[MQ * PSTR];

    float acc[8];
#pragma unroll
    for (int i = 0; i < 8; ++i) acc[i] = 0.f;
    float m_run = -1e30f, l_run = 0.f;

    const float nlb = -9.210340371976184f / 128.0f;  // -ln(10000)/d
    const float scale = 0.08838834764831845f;        // 1/sqrt(128)

    // ---- load + rope + scale the Q tile: 2 passes x (float4 per thread) ----
#pragma unroll
    for (int p = 0; p < 2; ++p) {
        const int idx = p * 1024 + tid * 4;
        const int row = idx >> 7;
        const int col = idx & 127;
        const int pos = start_pos + qt * MQ + row;
        float4 x = *(const float4*)(qg + (((long)(batch * NN + head) * SS + qt * MQ + row) * DD + col));
        float sn, cs;
        sincosf((float)pos * __expf(nlb * (float)col), &sn, &cs);
        q_s[row * KSTR + col]     = (x.x * cs - x.y * sn) * scale;
        q_s[row * KSTR + col + 1] = (x.x * sn + x.y * cs) * scale;
        sincosf((float)pos * __expf(nlb * (float)(col + 2)), &sn, &cs);
        q_s[row * KSTR + col + 2] = (x.z * cs - x.w * sn) * scale;
        q_s[row * KSTR + col + 3] = (x.z * sn + x.w * cs) * scale;
    }

    for (int kt = 0; kt < ntiles; ++kt) {
        const int t0 = kt * NK;
        __syncthreads();   // iter 0: Q visible; later: prior tile's k_s/v_s/p_s reads done

        // ---- stage K/V tile (NK x DD fp32): 4 passes x float4 per thread ----
#pragma unroll
        for (int it = 0; it < 4; ++it) {
            const int idx = it * 1024 + tid * 4;
            const int row = idx >> 7;
            const int col = idx & 127;
            const int t = t0 + row;
            float kb[4], vb[4];
            if (t < start_pos) {
                const float* ks = mg + (((long)batch * NMEM + t) * NN + head) * DD + col;
                const float* vs = ks + (long)MAXB * NMEM * NN * DD;
                float4 kk = *(const float4*)ks;
                float4 vv = *(const float4*)vs;
                kb[0] = kk.x; kb[1] = kk.y; kb[2] = kk.z; kb[3] = kk.w;
                vb[0] = vv.x; vb[1] = vv.y; vb[2] = vv.z; vb[3] = vv.w;
            } else if (t < T) {
                const int ts = t - start_pos;
                const long off = ((long)(batch * NN + head) * SS + ts) * DD + col;
                float4 kk = *(const float4*)(kg + off);
                float4 vv = *(const float4*)(vg + off);
                float sn, cs;
                sincosf((float)t * __expf(nlb * (float)col), &sn, &cs);
                kb[0] = kk.x * cs - kk.y * sn;
                kb[1] = kk.x * sn + kk.y * cs;
                sincosf((float)t * __expf(nlb * (float)(col + 2)), &sn, &cs);
                kb[2] = kk.z * cs - kk.w * sn;
                kb[3] = kk.z * sn + kk.w * cs;
                vb[0] = vv.x; vb[1] = vv.y; vb[2] = vv.z; vb[3] = vv.w;
            } else {
                kb[0] = kb[1] = kb[2] = kb[3] = 0.f;
                vb[0] = vb[1] = vb[2] = vb[3] = 0.f;
            }
#pragma unroll
            for (int j = 0; j < 4; ++j) {
                k_s[row * KSTR + col + j] = kb[j];
                v_s[row * KSTR + col + j] = vb[j];
            }
        }
        __syncthreads();

        // ---- scores: thread (qrow,l16) computes keys l16 and l16+16 ----
        float scv[2];
        {
            const float* qr = &q_s[qrow * KSTR];
            const float* k0 = &k_s[l16 * KSTR];
            const float* k1 = &k_s[(l16 + 16) * KSTR];
            float a0 = 0.f, a1 = 0.f, a2 = 0.f, a3 = 0.f;
            float b0 = 0.f, b1 = 0.f, b2 = 0.f, b3 = 0.f;
#pragma unroll
            for (int d2 = 0; d2 < DD; d2 += 4) {
                float4 qv  = *(const float4*)&qr[d2];
                float4 kv0 = *(const float4*)&k0[d2];
                float4 kv1 = *(const float4*)&k1[d2];
                a0 += qv.x * kv0.x; a1 += qv.y * kv0.y;
                a2 += qv.z * kv0.z; a3 += qv.w * kv0.w;
                b0 += qv.x * kv1.x; b1 += qv.y * kv1.y;
                b2 += qv.z * kv1.z; b3 += qv.w * kv1.w;
            }
            scv[0] = (t0 + l16 < T)      ? (a0 + a1) + (a2 + a3) : -1e30f;
            scv[1] = (t0 + l16 + 16 < T) ? (b0 + b1) + (b2 + b3) : -1e30f;
        }

        // ---- online softmax (16-lane groups share a query row) ----
        float mloc = fmaxf(scv[0], scv[1]);
#pragma unroll
        for (int off = 8; off; off >>= 1)
            mloc = fmaxf(mloc, __shfl_xor(mloc, off, 16));
        const float mnew = fmaxf(m_run, mloc);
        const float p0 = __expf(scv[0] - mnew);
        const float p1 = __expf(scv[1] - mnew);
        float lloc = p0 + p1;
#pragma unroll
        for (int off = 8; off; off >>= 1)
            lloc += __shfl_xor(lloc, off, 16);
        const float alpha = __expf(m_run - mnew);
        l_run = l_run * alpha + lloc;
        m_run = mnew;
#pragma unroll
        for (int i = 0; i < 8; ++i) acc[i] *= alpha;
        p_s[qrow * PSTR + l16]      = p0;
        p_s[qrow * PSTR + l16 + 16] = p1;
        __syncthreads();

        // ---- PV: thread (qrow,l16) owns out[qrow][8*l16 .. +8) ----
        const float* pr = &p_s[qrow * PSTR];
#pragma unroll 4
        for (int t = 0; t < NK; ++t) {
            const float p = pr[t];
            const float* vr = &v_s[t * KSTR + l16 * 8];
            float4 v0 = *(const float4*)&vr[0];
            float4 v1 = *(const float4*)&vr[4];
            acc[0] += p * v0.x; acc[1] += p * v0.y;
            acc[2] += p * v0.z; acc[3] += p * v0.w;
            acc[4] += p * v1.x; acc[5] += p * v1.y;
            acc[6] += p * v1.z; acc[7] += p * v1.w;
        }
    }

    // ---- epilogue: fp32 store, two float4 per thread ----
    const float inv_l = 1.f / l_run;
    float* dst = outg + (((long)(batch * NN + head) * SS + qt * MQ + qrow) * DD + l16 * 8);
    float4 o0 = make_float4(acc[0] * inv_l, acc[1] * inv_l, acc[2] * inv_l, acc[3] * inv_l);
    float4 o1 = make_float4(acc[4] * inv_l, acc[5] * inv_l, acc[6] * inv_l, acc[7] * inv_l);
    *(float4*)dst       = o0;
    *(float4*)(dst + 4) = o1;
}

extern "C" void kernel_launch(void* const* d_in, const int* in_sizes, int n_in,
                              void* d_out, int out_size, void* d_ws, size_t ws_size,
                              hipStream_t stream) {
    const float* q      = (const float*)d_in[0];
    const float* k      = (const float*)d_in[1];
    const float* v      = (const float*)d_in[2];
    const float* mem_kv = (const float*)d_in[3];
    const int*   sp     = (const int*)d_in[4];
    float* out = (float*)d_out;

    dim3 grid(SS / MQ, NN, BB);   // (32, 32, 4)
    dim3 block(256);
    hipLaunchKernelGGL(mra_attn, grid, block, 0, stream, q, k, v, mem_kv, sp, out);
}